// Round 2
// baseline (548.006 us; speedup 1.0000x reference)
//
#include <hip/hip_runtime.h>

// Problem constants
constexpr int H = 128, W = 128;
constexpr int IMG = H * W;        // 16384
constexpr int STRIP = 32;         // rows per block
constexpr int STRIPS = H / STRIP; // 4

__device__ __forceinline__ float max3f(float a, float b, float c) {
    return fmaxf(fmaxf(a, b), c);  // -> v_max3_f32
}
// hw transcendentals: v_exp_f32 = 2^x, v_log_f32 = log2(x)
__device__ __forceinline__ float exp2_hw(float x) { return __builtin_amdgcn_exp2f(x); }
__device__ __forceinline__ float log2_hw(float x) { return __builtin_amdgcn_logf(x); }
// ln(1+x) via fast hw log2; absolute error ~1e-7/elem, fine vs 0.56 threshold.
__device__ __forceinline__ float ln1p_fast(float x) {
    return log2_hw(1.0f + x) * 0.69314718055994530942f;
}

// One block = one 32-row strip of one 128x128 image.
// Stages 34 landmark rows in LDS (halo rows, OOB = -1e30 sentinel == -inf pad
// of lax.reduce_window). Each thread: 16 elements via float4.
__global__ __launch_bounds__(256, 4) void awing_partial(
    const float* __restrict__ pred,
    const float* __restrict__ lmk,
    float* __restrict__ part)
{
    __shared__ __align__(16) float s[(STRIP + 2) * W];  // 34*128 floats = 17 KB
    __shared__ float wsum[4];

    const int tid  = threadIdx.x;
    const int img  = blockIdx.x >> 2;   // STRIPS == 4
    const int st   = blockIdx.x & 3;
    const int row0 = st * STRIP;
    const float* li = lmk  + (size_t)img * IMG;
    const float* pi = pred + (size_t)img * IMG;

    // Stage 34 rows (row0-1 .. row0+32) as float4, coalesced.
    for (int s4 = tid; s4 < (STRIP + 2) * W / 4; s4 += 256) {
        int lr = s4 >> 5;          // lds row 0..33
        int c4 = s4 & 31;          // float4 column
        int gr = row0 - 1 + lr;    // global row
        float4 v = make_float4(-1e30f, -1e30f, -1e30f, -1e30f);
        if (gr >= 0 && gr < H) v = ((const float4*)li)[gr * 32 + c4];
        ((float4*)s)[s4] = v;
    }
    __syncthreads();

    float acc = 0.0f;
#pragma unroll
    for (int it = 0; it < 4; ++it) {
        int e  = it * 1024 + tid * 4;   // local element 0..4095
        int rl = e >> 7;                // local row 0..31
        int c  = e & 127;               // col, multiple of 4

        float4 p4 = ((const float4*)pi)[(row0 + rl) * 32 + (c >> 2)];

        int b0 = rl * W + c;            // lds row rl == global row-1
        float4 a4 = *(const float4*)&s[b0];
        float4 b4 = *(const float4*)&s[b0 + W];      // center row (landmark vals)
        float4 d4 = *(const float4*)&s[b0 + 2 * W];

        float aL, bL, cL, aR, bR, cR;
        if (c > 0)     { aL = s[b0 - 1];     bL = s[b0 + W - 1];     cL = s[b0 + 2*W - 1]; }
        else           { aL = bL = cL = -1e30f; }
        if (c < W - 4) { aR = s[b0 + 4];     bR = s[b0 + W + 4];     cR = s[b0 + 2*W + 4]; }
        else           { aR = bR = cR = -1e30f; }

        // vertical max, then horizontal windows (3x3 max, raw values —
        // round is monotone so rintf commutes with max)
        float vL = max3f(aL, bL, cL);
        float v0 = max3f(a4.x, b4.x, d4.x);
        float v1 = max3f(a4.y, b4.y, d4.y);
        float v2 = max3f(a4.z, b4.z, d4.z);
        float v3 = max3f(a4.w, b4.w, d4.w);
        float vR = max3f(aR, bR, cR);
        float mm[4] = { max3f(vL, v0, v1), max3f(v0, v1, v2),
                        max3f(v1, v2, v3), max3f(v2, v3, vR) };
        float yy[4] = { b4.x, b4.y, b4.z, b4.w };
        float pp[4] = { p4.x, p4.y, p4.z, p4.w };

#pragma unroll
        for (int j = 0; j < 4; ++j) {
            float y    = yy[j];
            float diff = fabsf(pp[j] - y);
            float asl  = 2.1f - y;                 // in (1.1, 2.1]
            float T1   = exp2_hw(-asl);            // 0.5^asl
            float invd = 1.0f / (1.0f + T1);
            float A    = 14.0f * asl * (2.0f * T1) * invd;  // T2 = 2*T1 exact
            float C    = 0.5f * A - 14.0f * ln1p_fast(T1);
            // diff^asl ; diff==0 -> log2=-inf -> exp2=0 (correct)
            float pw   = exp2_hw(asl * log2_hw(diff));
            float lo   = 14.0f * ln1p_fast(pw);
            float hi   = A * diff - C;
            float lossv = (diff < 0.5f) ? lo : hi;
            // weight: round-half-even (v_rndne) of 255*max3x3, threshold 25.6
            float wgt  = (rintf(mm[j] * 255.0f) >= 25.6f) ? 11.0f : 1.0f;
            acc = fmaf(lossv, wgt, acc);
        }
    }

    // block reduction: wave64 shuffle then 4 partials in LDS
#pragma unroll
    for (int off = 32; off > 0; off >>= 1) acc += __shfl_down(acc, off, 64);
    if ((tid & 63) == 0) wsum[tid >> 6] = acc;
    __syncthreads();
    if (tid == 0) part[blockIdx.x] = (wsum[0] + wsum[1]) + (wsum[2] + wsum[3]);
}

__global__ void final_reduce(const float* __restrict__ part, int n,
                             float* __restrict__ out, double inv_total)
{
    __shared__ double sd[4];
    int tid = threadIdx.x;
    double a = 0.0;
    for (int i = tid; i < n; i += 256) a += (double)part[i];
#pragma unroll
    for (int off = 32; off > 0; off >>= 1) a += __shfl_down(a, off, 64);
    if ((tid & 63) == 0) sd[tid >> 6] = a;
    __syncthreads();
    if (tid == 0) out[0] = (float)((sd[0] + sd[1] + sd[2] + sd[3]) * inv_total);
}

extern "C" void kernel_launch(void* const* d_in, const int* in_sizes, int n_in,
                              void* d_out, int out_size, void* d_ws, size_t ws_size,
                              hipStream_t stream)
{
    const float* pred = (const float*)d_in[0];
    const float* lmk  = (const float*)d_in[1];
    float* part = (float*)d_ws;           // 17408 floats = 68 KB scratch
    int total   = in_sizes[0];            // 71303168
    int nimg    = total / IMG;            // 4352
    int nblocks = nimg * STRIPS;          // 17408

    awing_partial<<<nblocks, 256, 0, stream>>>(pred, lmk, part);
    final_reduce<<<1, 256, 0, stream>>>(part, nblocks, (float*)d_out,
                                        1.0 / (double)total);
}